// Round 5
// baseline (441.893 us; speedup 1.0000x reference)
//
#include <hip/hip_runtime.h>
#include <hip/hip_cooperative_groups.h>

namespace cg = cooperative_groups;

typedef __bf16 bf16;
typedef __bf16 bf16x4 __attribute__((ext_vector_type(4)));
typedef __bf16 bf16x8 __attribute__((ext_vector_type(8)));
typedef float f32x4 __attribute__((ext_vector_type(4)));

// B_Nq = B_Ns = 16, C = 512, P = 1024, TAU*C = 256. I/O fp32; GEMMs bf16 MFMA.
// SINGLE cooperative dispatch: P0 prep -> P1 gemm1(+rm/u) -> P2 softmax_ac(+zero)
// -> P3 gemm2(+alog+blog) -> P4 softmax_rows(+bmean). grid.sync() between phases.

#define GLL16(g, l)                                                             \
    __builtin_amdgcn_global_load_lds((const __attribute__((address_space(1))) void*)(g), \
                                     (__attribute__((address_space(3))) void*)(l), 16, 0, 0)

__device__ inline float wave_reduce_sum(float v) {
#pragma unroll
    for (int m = 32; m >= 1; m >>= 1) v += __shfl_xor(v, m, 64);
    return v;
}
__device__ inline float wave_reduce_max(float v) {
#pragma unroll
    for (int m = 32; m >= 1; m >>= 1) v = fmaxf(v, __shfl_xor(v, m, 64));
    return v;
}

struct KParams {
    const float* fq;
    const float* fs;
    const float* wq;    // w_cca_q
    const float* wk;    // w_cca_k
    const float* wv;    // w_cca_v
    const float* wsq;   // w_sca_q
    const float* wsk;   // w_sca_k
    const float* lamp;
    float* fsm32;
    bf16* fsm16;
    bf16* fsmT;
    bf16* fq16;
    float* rmpart;
    float* rm;
    float* u;
    float* G;
    bf16* Acw;
    float* r;
    float* alog;   // zbuf start: alog,blog,bmean,cnt contiguous
    float* blog;
    float* bmean;
    int* cnt;
    float* out_fq;
    float* out_alpha;
    float* out_bmean;
};

// LDS layout (53248 B total, 2 blocks/CU):
//   [0,16384)      As[2][4096] bf16  (gemm A double-buffer)
//   [16384,49152)  Bs[2][8192] bf16  (gemm B double-buffer)
//   [49152,53248)  extra: prep tile[32][33] bf16 / P3 coef[512] f32 / P4 red+flag
__global__ void __launch_bounds__(256, 2) k_mega(KParams P) {
    __shared__ __align__(16) char smem[53248];
    cg::grid_group grid = cg::this_grid();
    const int bid = blockIdx.x;
    const int t = threadIdx.x;
    const int w = t >> 6, lane = t & 63;
    const int quad = lane >> 4, r15 = lane & 15;

    // ================= P0: prep (512 blocks, 1:1) =================
    {
        bf16(*tile)[33] = (bf16(*)[33])(smem + 49152);
        int bx = bid & 31, by = bid >> 5;
        int p0 = bx * 32, c0 = by * 32;
        int cy = t >> 3, px = (t & 7) * 4;
        size_t off = (size_t)(c0 + cy) * 1024 + p0 + px;
        float4 s = {0.f, 0.f, 0.f, 0.f};
#pragma unroll
        for (int b = 0; b < 16; ++b) {
            float4 v = *(const float4*)(P.fs + (size_t)b * 524288 + off);
            s.x += v.x; s.y += v.y; s.z += v.z; s.w += v.w;
        }
        s.x *= (1.f / 16.f); s.y *= (1.f / 16.f); s.z *= (1.f / 16.f); s.w *= (1.f / 16.f);
        *(float4*)(P.fsm32 + off) = s;
        bf16x4 h4 = {(bf16)s.x, (bf16)s.y, (bf16)s.z, (bf16)s.w};
        *(bf16x4*)(P.fsm16 + off) = h4;
        tile[cy][px] = h4[0];
        tile[cy][px + 1] = h4[1];
        tile[cy][px + 2] = h4[2];
        tile[cy][px + 3] = h4[3];
        float rp = s.x + s.y + s.z + s.w;
        rp += __shfl_xor(rp, 1, 64);
        rp += __shfl_xor(rp, 2, 64);
        rp += __shfl_xor(rp, 4, 64);
        if ((t & 7) == 0) P.rmpart[bx * 512 + c0 + cy] = rp;
        __syncthreads();
        int tx = t & 31, ty = t >> 5;
#pragma unroll
        for (int i = 0; i < 4; ++i)
            P.fsmT[(size_t)(p0 + ty + 8 * i) * 512 + c0 + tx] = tile[tx][ty + 8 * i];
        int blk = by * 32 + bx;
        const float4* f4 = (const float4*)P.fq;
#pragma unroll
        for (int i = 0; i < 16; ++i) {
            int idx = blk * 4096 + i * 256 + t;
            float4 v = f4[idx];
            bf16x4 q4 = {(bf16)v.x, (bf16)v.y, (bf16)v.z, (bf16)v.w};
            *(bf16x4*)(P.fq16 + (size_t)idx * 4) = q4;
        }
    }
    grid.sync();

    // ================= P1: gemm1 (512 blocks, 1:1) =================
    // G[b,c,d] = sum_p fq16[b,c,p]*fsm16[d,p]; 64x128 tile, BK=64, counted vmcnt(6).
    {
        bf16* As = (bf16*)smem;
        bf16* Bs = (bf16*)(smem + 16384);
        const int dt = bid & 3, ct = (bid >> 2) & 7, b = bid >> 5;
        const int wr = w & 1, wc = w >> 1;
        if (dt == 0 && b == 0) {  // rm/u finalize (consumed in P2/P3 after syncs)
            int c = ct * 64 + (t >> 2);
            float sum = 0.f;
#pragma unroll
            for (int j = 0; j < 8; ++j) sum += P.rmpart[((t & 3) * 8 + j) * 512 + c];
            sum += __shfl_xor(sum, 1, 64);
            sum += __shfl_xor(sum, 2, 64);
            if ((t & 3) == 0) {
                float rmv = sum * (1.f / 1024.f);
                P.rm[c] = rmv;
                P.u[c] = P.wsq[c] * P.wsk[c] * rmv * (1.f / 256.f);
            }
        }
        const bf16* Abase = P.fq16 + ((size_t)(b * 512 + ct * 64)) * 1024;
        const bf16* Bbase = P.fsm16 + ((size_t)(dt * 128)) * 1024;
        f32x4 acc[2][4] = {};
        auto STAGE = [&](int buf, int k0) {
#pragma unroll
            for (int i = 0; i < 2; ++i) {
                int row = i * 32 + (t >> 3);
                int gchunk = (t & 7) ^ (row & 7);
                GLL16(Abase + (size_t)row * 1024 + k0 + gchunk * 8, As + buf * 4096 + (i * 256 + t) * 8);
            }
#pragma unroll
            for (int i = 0; i < 4; ++i) {
                int row = i * 32 + (t >> 3);
                int gchunk = (t & 7) ^ (row & 7);
                GLL16(Bbase + (size_t)row * 1024 + k0 + gchunk * 8, Bs + buf * 8192 + (i * 256 + t) * 8);
            }
        };
        STAGE(0, 0);
        STAGE(1, 64);
        for (int s = 0; s < 16; ++s) {
            if (s < 15) asm volatile("s_waitcnt vmcnt(6)" ::: "memory");
            else        asm volatile("s_waitcnt vmcnt(0)" ::: "memory");
            __builtin_amdgcn_s_barrier();
            const int cur = s & 1;
#pragma unroll
            for (int ks = 0; ks < 2; ++ks) {
                bf16x8 af[2], bfr[4];
                const int c8 = ks * 4 + quad;
#pragma unroll
                for (int mi = 0; mi < 2; ++mi) {
                    int R = wr * 32 + mi * 16 + r15;
                    af[mi] = *(const bf16x8*)(As + cur * 4096 + R * 64 + ((c8 ^ (R & 7)) * 8));
                }
#pragma unroll
                for (int j = 0; j < 4; ++j) {
                    int R = wc * 64 + j * 16 + r15;
                    bfr[j] = *(const bf16x8*)(Bs + cur * 8192 + R * 64 + ((c8 ^ (R & 7)) * 8));
                }
#pragma unroll
                for (int mi = 0; mi < 2; ++mi)
#pragma unroll
                    for (int j = 0; j < 4; ++j)
                        acc[mi][j] = __builtin_amdgcn_mfma_f32_16x16x32_bf16(af[mi], bfr[j], acc[mi][j], 0, 0, 0);
            }
            __builtin_amdgcn_s_barrier();
            if (s + 2 < 16) STAGE(cur, (s + 2) * 64);
        }
#pragma unroll
        for (int mi = 0; mi < 2; ++mi) {
            float* g = P.G + ((size_t)(b * 512 + ct * 64 + wr * 32 + mi * 16 + quad * 4)) * 512 +
                       dt * 128 + wc * 64 + r15;
#pragma unroll
            for (int j = 0; j < 4; ++j)
#pragma unroll
                for (int ii = 0; ii < 4; ++ii)
                    g[(size_t)ii * 512 + j * 16] = acc[mi][j][ii];
        }
    }
    grid.sync();

    // ================= P2: softmax_ac (2048 v-blocks, 4 iters) =================
    for (int v = bid; v < 2048; v += 512) {
        if (v < 133) P.alog[v * 256 + t] = 0.f;  // zero alog,blog,bmean,cnt (contiguous)
        int row = v * 4 + (t >> 6);
        int c = row & 511;
        const float* g = P.G + (size_t)row * 512;
        float sc = P.wq[c] * (1.f / 1024.f);
        float vv[8];
        float mx = -3.4e38f;
#pragma unroll
        for (int j = 0; j < 8; ++j) {
            int d = lane + 64 * j;
            vv[j] = g[d] * sc * P.wk[d];
            mx = fmaxf(mx, vv[j]);
        }
        mx = wave_reduce_max(mx);
        float sum = 0.f;
#pragma unroll
        for (int j = 0; j < 8; ++j) {
            vv[j] = __expf(vv[j] - mx);
            sum += vv[j];
        }
        sum = wave_reduce_sum(sum);
        float inv = 1.f / sum;
        bf16* o = P.Acw + (size_t)row * 512;
        float rsum = 0.f;
#pragma unroll
        for (int j = 0; j < 8; ++j) {
            int d = lane + 64 * j;
            float aw = vv[j] * inv * P.wv[d];
            o[d] = (bf16)aw;
            rsum += aw * P.rm[d];
        }
        rsum = wave_reduce_sum(rsum);
        if (lane == 0) P.r[row] = rsum;
    }
    grid.sync();

    // ================= P3: gemm2 (1024 v-blocks, 2 iters) =================
    // out = fq + lam*(Acw @ fsmT^T); epilogues: alog atomics (all), blog (ct==0).
    {
        bf16* As = (bf16*)smem;
        bf16* Bs = (bf16*)(smem + 16384);
        float lam = P.lamp[0];
        for (int v = bid; v < 1024; v += 512) {
            const int pt = v & 7, ct = (v >> 3) & 7, b = v >> 6;
            const int wr = w & 1, wc = w >> 1;
            const bf16* Abase = P.Acw + ((size_t)(b * 512 + ct * 64)) * 512;
            const bf16* Bbase = P.fsmT + ((size_t)(pt * 128)) * 512;
            f32x4 acc[2][4] = {};
            auto STAGE = [&](int buf, int k0) {
#pragma unroll
                for (int i = 0; i < 2; ++i) {
                    int row = i * 32 + (t >> 3);
                    int gchunk = (t & 7) ^ (row & 7);
                    GLL16(Abase + (size_t)row * 512 + k0 + gchunk * 8, As + buf * 4096 + (i * 256 + t) * 8);
                }
#pragma unroll
                for (int i = 0; i < 4; ++i) {
                    int row = i * 32 + (t >> 3);
                    int gchunk = (t & 7) ^ (row & 7);
                    GLL16(Bbase + (size_t)row * 512 + k0 + gchunk * 8, Bs + buf * 8192 + (i * 256 + t) * 8);
                }
            };
            STAGE(0, 0);
            STAGE(1, 64);
            for (int s = 0; s < 8; ++s) {
                if (s < 7) asm volatile("s_waitcnt vmcnt(6)" ::: "memory");
                else       asm volatile("s_waitcnt vmcnt(0)" ::: "memory");
                __builtin_amdgcn_s_barrier();
                const int cur = s & 1;
#pragma unroll
                for (int ks = 0; ks < 2; ++ks) {
                    bf16x8 af[2], bfr[4];
                    const int c8 = ks * 4 + quad;
#pragma unroll
                    for (int mi = 0; mi < 2; ++mi) {
                        int R = wr * 32 + mi * 16 + r15;
                        af[mi] = *(const bf16x8*)(As + cur * 4096 + R * 64 + ((c8 ^ (R & 7)) * 8));
                    }
#pragma unroll
                    for (int j = 0; j < 4; ++j) {
                        int R = wc * 64 + j * 16 + r15;
                        bfr[j] = *(const bf16x8*)(Bs + cur * 8192 + R * 64 + ((c8 ^ (R & 7)) * 8));
                    }
#pragma unroll
                    for (int mi = 0; mi < 2; ++mi)
#pragma unroll
                        for (int j = 0; j < 4; ++j)
                            acc[mi][j] = __builtin_amdgcn_mfma_f32_16x16x32_bf16(af[mi], bfr[j], acc[mi][j], 0, 0, 0);
                }
                __builtin_amdgcn_s_barrier();
                if (s + 2 < 8) STAGE(cur, (s + 2) * 64);
            }
#pragma unroll
            for (int mi = 0; mi < 2; ++mi) {
                size_t rowbase = (size_t)(b * 512 + ct * 64 + wr * 32 + mi * 16 + quad * 4);
#pragma unroll
                for (int j = 0; j < 4; ++j)
#pragma unroll
                    for (int ii = 0; ii < 4; ++ii) {
                        size_t idx = (rowbase + ii) * 1024 + pt * 128 + wc * 64 + j * 16 + r15;
                        P.out_fq[idx] = P.fq[idx] + lam * acc[mi][j][ii];
                    }
            }
            float uv[2][4];
#pragma unroll
            for (int mi = 0; mi < 2; ++mi)
#pragma unroll
                for (int ii = 0; ii < 4; ++ii)
                    uv[mi][ii] = P.u[ct * 64 + wr * 32 + mi * 16 + quad * 4 + ii];
#pragma unroll
            for (int j = 0; j < 4; ++j) {
                float pv = 0.f;
#pragma unroll
                for (int mi = 0; mi < 2; ++mi)
#pragma unroll
                    for (int ii = 0; ii < 4; ++ii)
                        pv += uv[mi][ii] * acc[mi][j][ii];
                pv += __shfl_xor(pv, 16, 64);
                pv += __shfl_xor(pv, 32, 64);
                if (lane < 16)
                    atomicAdd(P.alog + (size_t)b * 1024 + pt * 128 + wc * 64 + j * 16 + r15, pv);
            }
            if (ct == 0) {
                float* coef = (float*)(smem + 49152);
                __syncthreads();
                coef[t] = P.r[b * 512 + t] * P.wsq[t] * P.wsk[t] * (1.f / 256.f);
                coef[t + 256] = P.r[b * 512 + t + 256] * P.wsq[t + 256] * P.wsk[t + 256] * (1.f / 256.f);
                __syncthreads();
                int q = pt * 128 + (t & 127);
                int ch = t >> 7;
                const float* f = P.fsm32 + (size_t)(ch * 256) * 1024 + q;
                const float* cf = coef + ch * 256;
                float s0 = 0.f, s1 = 0.f, s2 = 0.f, s3 = 0.f;
#pragma unroll 4
                for (int ci = 0; ci < 256; ci += 4) {
                    s0 += cf[ci] * f[(size_t)ci * 1024];
                    s1 += cf[ci + 1] * f[(size_t)(ci + 1) * 1024];
                    s2 += cf[ci + 2] * f[(size_t)(ci + 2) * 1024];
                    s3 += cf[ci + 3] * f[(size_t)(ci + 3) * 1024];
                }
                atomicAdd(&P.blog[(size_t)b * 1024 + q], (s0 + s1) + (s2 + s3));
            }
        }
    }
    grid.sync();

    // ================= P4: softmax_rows + bmean (32 blocks) =================
    if (bid < 32) {
        int z = bid;
        float* red = (float*)(smem + 49152);
        int* lastflag = (int*)(smem + 49152 + 64);
        const float* src = (z < 16) ? (P.alog + (size_t)z * 1024) : (P.blog + (size_t)(z - 16) * 1024);
        float v[4];
        float mx = -3.4e38f;
#pragma unroll
        for (int j = 0; j < 4; ++j) {
            v[j] = src[t + 256 * j];
            mx = fmaxf(mx, v[j]);
        }
        float wm = wave_reduce_max(mx);
        if (lane == 0) red[w] = wm;
        __syncthreads();
        mx = fmaxf(fmaxf(red[0], red[1]), fmaxf(red[2], red[3]));
        float s = 0.f;
#pragma unroll
        for (int j = 0; j < 4; ++j) {
            v[j] = __expf(v[j] - mx);
            s += v[j];
        }
        __syncthreads();
        float ws_ = wave_reduce_sum(s);
        if (lane == 0) red[w] = ws_;
        __syncthreads();
        s = red[0] + red[1] + red[2] + red[3];
        float inv = 1.f / s;
        if (z < 16) {
#pragma unroll
            for (int j = 0; j < 4; ++j) P.out_alpha[(size_t)z * 1024 + t + 256 * j] = v[j] * inv;
        } else {
            float inv16 = inv * (1.f / 16.f);
#pragma unroll
            for (int j = 0; j < 4; ++j) atomicAdd(&P.bmean[t + 256 * j], v[j] * inv16);
            __threadfence();
            __syncthreads();
            if (t == 0) *lastflag = (atomicAdd(P.cnt, 1) == 15) ? 1 : 0;
            __syncthreads();
            if (*lastflag) {
                __threadfence();
#pragma unroll
                for (int j = 0; j < 4; ++j) {
                    int q = t + 256 * j;
                    float val = __hip_atomic_load(&P.bmean[q], __ATOMIC_ACQUIRE, __HIP_MEMORY_SCOPE_AGENT);
#pragma unroll
                    for (int si = 0; si < 16; ++si) P.out_bmean[(size_t)si * 1024 + q] = val;
                }
            }
        }
    }
}

extern "C" void kernel_launch(void* const* d_in, const int* in_sizes, int n_in,
                              void* d_out, int out_size, void* d_ws, size_t ws_size,
                              hipStream_t stream) {
    char* ws = (char*)d_ws;
    KParams P;
    P.fq = (const float*)d_in[0];
    P.fs = (const float*)d_in[1];
    P.wq = (const float*)d_in[2];
    P.wk = (const float*)d_in[3];
    P.wv = (const float*)d_in[4];
    P.wsq = (const float*)d_in[5];
    P.wsk = (const float*)d_in[6];
    P.lamp = (const float*)d_in[7];
    P.fsm32 = (float*)(ws + 0);           //  2 MB   [512,1024]
    P.fsm16 = (bf16*)(ws + 2097152);      //  1 MB
    P.fsmT = (bf16*)(ws + 3145728);       //  1 MB   [1024,512]
    P.G = (float*)(ws + 4194304);         // 16 MB   [16,512,512]
    P.Acw = (bf16*)(ws + 20971520);       //  8 MB   [16,512,512]
    P.fq16 = (bf16*)(ws + 29360128);      // 16.8 MB [16,512,1024]
    P.rmpart = (float*)(ws + 46137344);   // 64 KB   [32,512]
    P.rm = (float*)(ws + 46202880);       //  2 KB
    P.u = (float*)(ws + 46204928);        //  2 KB
    P.r = (float*)(ws + 46206976);        // 32 KB   [16,512]
    P.alog = (float*)(ws + 46239744);     // 64 KB  -- zbuf start (alog,blog,bmean,cnt)
    P.blog = (float*)(ws + 46305280);     // 64 KB
    P.bmean = (float*)(ws + 46370816);    //  4 KB
    P.cnt = (int*)(ws + 46374912);        //  1 KB

    float* out_fq = (float*)d_out;
    P.out_fq = out_fq;
    P.out_alpha = out_fq + 8388608;
    P.out_bmean = out_fq + 8404992;

    void* args[] = {(void*)&P};
    hipLaunchCooperativeKernel((const void*)k_mega, dim3(512), dim3(256), args, 0, stream);
}

// Round 6
// 197.086 us; speedup vs baseline: 2.2421x; 2.2421x over previous
//
#include <hip/hip_runtime.h>

typedef __bf16 bf16;
typedef __bf16 bf16x4 __attribute__((ext_vector_type(4)));
typedef __bf16 bf16x8 __attribute__((ext_vector_type(8)));
typedef float f32x4 __attribute__((ext_vector_type(4)));

// B_Nq = B_Ns = 16, C = 512, P = 1024, TAU*C = 256. I/O fp32; GEMMs bf16 MFMA.
// 4 dispatches: prep -> fused1 (gemm1+softmax+r/u, no G) -> gemm2(+alog+blog) -> softmax_rows.

#define GLL16(g, l)                                                             \
    __builtin_amdgcn_global_load_lds((const __attribute__((address_space(1))) void*)(g), \
                                     (__attribute__((address_space(3))) void*)(l), 16, 0, 0)

__device__ inline float wave_reduce_sum(float v) {
#pragma unroll
    for (int m = 32; m >= 1; m >>= 1) v += __shfl_xor(v, m, 64);
    return v;
}
__device__ inline float wave_reduce_max(float v) {
#pragma unroll
    for (int m = 32; m >= 1; m >>= 1) v = fmaxf(v, __shfl_xor(v, m, 64));
    return v;
}

// K0: fs_mean (fp32+bf16+transpose), f_q->bf16, transposed row partials rmpartT[512][32].
// grid (32 p-tiles, 16 c-tiles), block 256.
__global__ void k_prep(const float* __restrict__ fs, const float* __restrict__ fq,
                       float* __restrict__ fsm32, bf16* __restrict__ fsm16,
                       bf16* __restrict__ fsmT, bf16* __restrict__ fq16,
                       float* __restrict__ rmpartT) {
    __shared__ bf16 tile[32][33];
    int bx = blockIdx.x, by = blockIdx.y;
    int p0 = bx * 32, c0 = by * 32;
    int t = threadIdx.x;
    int cy = t >> 3, px = (t & 7) * 4;
    size_t off = (size_t)(c0 + cy) * 1024 + p0 + px;
    float4 s = {0.f, 0.f, 0.f, 0.f};
#pragma unroll
    for (int b = 0; b < 16; ++b) {
        float4 v = *(const float4*)(fs + (size_t)b * 524288 + off);
        s.x += v.x; s.y += v.y; s.z += v.z; s.w += v.w;
    }
    s.x *= (1.f / 16.f); s.y *= (1.f / 16.f); s.z *= (1.f / 16.f); s.w *= (1.f / 16.f);
    *(float4*)(fsm32 + off) = s;
    bf16x4 h4 = {(bf16)s.x, (bf16)s.y, (bf16)s.z, (bf16)s.w};
    *(bf16x4*)(fsm16 + off) = h4;
    tile[cy][px] = h4[0];
    tile[cy][px + 1] = h4[1];
    tile[cy][px + 2] = h4[2];
    tile[cy][px + 3] = h4[3];
    float rp = s.x + s.y + s.z + s.w;
    rp += __shfl_xor(rp, 1, 64);
    rp += __shfl_xor(rp, 2, 64);
    rp += __shfl_xor(rp, 4, 64);
    if ((t & 7) == 0) rmpartT[(size_t)(c0 + cy) * 32 + bx] = rp;
    __syncthreads();
    int tx = t & 31, ty = t >> 5;
#pragma unroll
    for (int i = 0; i < 4; ++i)
        fsmT[(size_t)(p0 + ty + 8 * i) * 512 + c0 + tx] = tile[tx][ty + 8 * i];
    int blk = by * 32 + bx;
    const float4* f4 = (const float4*)fq;
#pragma unroll
    for (int i = 0; i < 16; ++i) {
        int idx = blk * 4096 + i * 256 + t;
        float4 v = f4[idx];
        bf16x4 q4 = {(bf16)v.x, (bf16)v.y, (bf16)v.z, (bf16)v.w};
        *(bf16x4*)(fq16 + (size_t)idx * 4) = q4;
    }
}

// K1 fused: block (ct2, b) computes rows c = ct2*32..+32, ALL 512 d cols, then
// row-softmax( G*wq*wk/P ) * wv -> Acw, and r[b,c]. No G buffer.
// 512 threads / 8 waves; wave w: cols w*64..+64, acc[2][4]. K=1024, BK=32.
// B (fsm16) double-buffered in 64 KB LDS (XOR-swizzled via pre-swizzled source);
// A (fq16) fragments register-prefetched from global. Counted vmcnt(4).
// Epilogue reuses the B-LDS for cross-wave reductions. b==0 blocks write u.
// grid (16 ct2, 16 b) = 256 blocks.
__global__ void __launch_bounds__(512, 1) k_fused1(
        const bf16* __restrict__ fq16, const bf16* __restrict__ fsm16,
        const float* __restrict__ wq, const float* __restrict__ wk,
        const float* __restrict__ wv, const float* __restrict__ rmpartT,
        const float* __restrict__ wsq, const float* __restrict__ wsk,
        bf16* __restrict__ Acw, float* __restrict__ r, float* __restrict__ u,
        float* __restrict__ zbuf) {
    __shared__ __align__(16) char smem[65536];
    bf16* smB = (bf16*)smem;
    const int ct2 = blockIdx.x, b = blockIdx.y;
    const int t = threadIdx.x;
    const int w = t >> 6, lane = t & 63;
    const int quad = lane >> 4, r15 = lane & 15;
    // zero alog/blog/bmean/cnt (34048 floats contiguous) for gemm2's atomics
    {
        int lb = b * 16 + ct2;
        int idx = lb * 512 + t;
        if (idx < 34048) zbuf[idx] = 0.f;
    }
    const bf16* Abase = fq16 + ((size_t)(b * 512 + ct2 * 32)) * 1024;
    const bf16* Arow = Abase + (size_t)r15 * 1024 + quad * 8;

    auto BSTAGE = [&](int buf, int k0) {
#pragma unroll
        for (int i = 0; i < 4; ++i) {
            int row = i * 128 + (t >> 2);
            int gc = (t & 3) ^ ((row >> 1) & 3);
            GLL16(fsm16 + (size_t)row * 1024 + k0 + gc * 8, smB + buf * 16384 + (i * 512 + t) * 8);
        }
    };
    f32x4 acc[2][4] = {};
    bf16x8 afA[2], afB[2];
    BSTAGE(0, 0);
#pragma unroll
    for (int mi = 0; mi < 2; ++mi) afA[mi] = *(const bf16x8*)(Arow + (size_t)(mi * 16) * 1024);
    BSTAGE(1, 32);
    for (int s = 0; s < 32; ++s) {
        if (s < 31) asm volatile("s_waitcnt vmcnt(4)" ::: "memory");
        else        asm volatile("s_waitcnt vmcnt(0)" ::: "memory");
        __builtin_amdgcn_s_barrier();
        const int cur = s & 1;
        if (s + 1 < 32) {
#pragma unroll
            for (int mi = 0; mi < 2; ++mi)
                afB[mi] = *(const bf16x8*)(Arow + (size_t)(mi * 16) * 1024 + (s + 1) * 32);
        }
#pragma unroll
        for (int j = 0; j < 4; ++j) {
            int R = w * 64 + j * 16 + r15;
            bf16x8 bfr = *(const bf16x8*)(smB + cur * 16384 + R * 32 + ((quad ^ ((R >> 1) & 3)) * 8));
            acc[0][j] = __builtin_amdgcn_mfma_f32_16x16x32_bf16(afA[0], bfr, acc[0][j], 0, 0, 0);
            acc[1][j] = __builtin_amdgcn_mfma_f32_16x16x32_bf16(afA[1], bfr, acc[1][j], 0, 0, 0);
        }
        __builtin_amdgcn_s_barrier();
        if (s + 2 < 32) BSTAGE(cur, (s + 2) * 32);
        afA[0] = afB[0];
        afA[1] = afB[1];
    }
    // ---------------- epilogue: softmax over d (512) for 32 rows ----------------
    // weights for this lane's 4 d-cols and 8 rows
    float wkd[4], wvd[4], rmd[4];
#pragma unroll
    for (int j = 0; j < 4; ++j) {
        int d = w * 64 + j * 16 + r15;
        wkd[j] = wk[d];
        wvd[j] = wv[d];
        f32x4 s4 = {0.f, 0.f, 0.f, 0.f};
        const f32x4* rp4 = (const f32x4*)(rmpartT + (size_t)d * 32);
#pragma unroll
        for (int q8 = 0; q8 < 8; ++q8) s4 += rp4[q8];
        rmd[j] = (s4[0] + s4[1] + s4[2] + s4[3]) * (1.f / 1024.f);
    }
    float scr[2][4];
#pragma unroll
    for (int mi = 0; mi < 2; ++mi)
#pragma unroll
        for (int ii = 0; ii < 4; ++ii)
            scr[mi][ii] = wq[ct2 * 32 + mi * 16 + quad * 4 + ii] * (1.f / 1024.f);
    // scale in place, per-row max over this wave's 64 cols
    float m8[2][4];
#pragma unroll
    for (int mi = 0; mi < 2; ++mi)
#pragma unroll
        for (int ii = 0; ii < 4; ++ii) {
            float m = -3.4e38f;
#pragma unroll
            for (int j = 0; j < 4; ++j) {
                float v = acc[mi][j][ii] * scr[mi][ii] * wkd[j];
                acc[mi][j][ii] = v;
                m = fmaxf(m, v);
            }
#pragma unroll
            for (int mk = 1; mk <= 8; mk <<= 1) m = fmaxf(m, __shfl_xor(m, mk, 64));
            m8[mi][ii] = m;
        }
    float* red = (float*)smem;  // [0,256) rowmax, [256,512) rowsum, [512,768) rowr
    if (r15 == 0) {
#pragma unroll
        for (int mi = 0; mi < 2; ++mi)
#pragma unroll
            for (int ii = 0; ii < 4; ++ii)
                red[w * 32 + mi * 16 + quad * 4 + ii] = m8[mi][ii];
    }
    __syncthreads();
    float gm[2][4];
#pragma unroll
    for (int mi = 0; mi < 2; ++mi)
#pragma unroll
        for (int ii = 0; ii < 4; ++ii) {
            int row = mi * 16 + quad * 4 + ii;
            float g = red[row];
#pragma unroll
            for (int ww = 1; ww < 8; ++ww) g = fmaxf(g, red[ww * 32 + row]);
            gm[mi][ii] = g;
        }
    float rs8[2][4], rr8[2][4];
#pragma unroll
    for (int mi = 0; mi < 2; ++mi)
#pragma unroll
        for (int ii = 0; ii < 4; ++ii) {
            float rs = 0.f, rr = 0.f;
#pragma unroll
            for (int j = 0; j < 4; ++j) {
                float p = __expf(acc[mi][j][ii] - gm[mi][ii]);
                acc[mi][j][ii] = p;
                rs += p;
                rr += p * wvd[j] * rmd[j];
            }
#pragma unroll
            for (int mk = 1; mk <= 8; mk <<= 1) {
                rs += __shfl_xor(rs, mk, 64);
                rr += __shfl_xor(rr, mk, 64);
            }
            rs8[mi][ii] = rs;
            rr8[mi][ii] = rr;
        }
    if (r15 == 0) {
#pragma unroll
        for (int mi = 0; mi < 2; ++mi)
#pragma unroll
            for (int ii = 0; ii < 4; ++ii) {
                int row = mi * 16 + quad * 4 + ii;
                red[256 + w * 32 + row] = rs8[mi][ii];
                red[512 + w * 32 + row] = rr8[mi][ii];
            }
    }
    __syncthreads();
#pragma unroll
    for (int mi = 0; mi < 2; ++mi)
#pragma unroll
        for (int ii = 0; ii < 4; ++ii) {
            int row = mi * 16 + quad * 4 + ii;
            float gs = 0.f;
#pragma unroll
            for (int ww = 0; ww < 8; ++ww) gs += red[256 + ww * 32 + row];
            float inv = 1.f / gs;
            bf16* o = Acw + ((size_t)(b * 512 + ct2 * 32 + row)) * 512;
#pragma unroll
            for (int j = 0; j < 4; ++j)
                o[w * 64 + j * 16 + r15] = (bf16)(acc[mi][j][ii] * inv * wvd[j]);
        }
    if (t < 32) {
        float gs = 0.f, gr = 0.f;
#pragma unroll
        for (int ww = 0; ww < 8; ++ww) {
            gs += red[256 + ww * 32 + t];
            gr += red[512 + ww * 32 + t];
        }
        r[b * 512 + ct2 * 32 + t] = gr / gs;
    }
    if (b == 0 && t < 32) {
        int c = ct2 * 32 + t;
        f32x4 s4 = {0.f, 0.f, 0.f, 0.f};
        const f32x4* rp4 = (const f32x4*)(rmpartT + (size_t)c * 32);
#pragma unroll
        for (int q8 = 0; q8 < 8; ++q8) s4 += rp4[q8];
        float rmc = (s4[0] + s4[1] + s4[2] + s4[3]) * (1.f / 1024.f);
        u[c] = wsq[c] * wsk[c] * rmc * (1.f / 256.f);
    }
}

// K5: out[b,c,p] = fq + lam*CP; CP = Acw @ fsmT^T. Counted-vmcnt 2-deep pipeline.
// Epilogues: alog atomics (all blocks), blog (ct==0). grid (8 pt, 8 ct, 16 b).
__global__ void k_gemm2(const bf16* __restrict__ A, const bf16* __restrict__ B,
                        const float* __restrict__ fq, const float* __restrict__ lamp,
                        const float* __restrict__ u, const float* __restrict__ r,
                        const float* __restrict__ wsq, const float* __restrict__ wsk,
                        const float* __restrict__ fsm32, float* __restrict__ out,
                        float* __restrict__ alog, float* __restrict__ blog) {
    __shared__ alignas(16) bf16 As[2][64 * 64];
    __shared__ alignas(16) bf16 Bs[2][128 * 64];
    const int pt = blockIdx.x, ct = blockIdx.y, b = blockIdx.z;
    const int t = threadIdx.x, w = t >> 6, lane = t & 63;
    const int quad = lane >> 4, r15 = lane & 15;
    const int wr = w & 1, wc = w >> 1;
    const bf16* Abase = A + ((size_t)(b * 512 + ct * 64)) * 512;
    const bf16* Bbase = B + ((size_t)(pt * 128)) * 512;
    f32x4 acc[2][4] = {};
    auto STAGE = [&](int buf, int k0) {
#pragma unroll
        for (int i = 0; i < 2; ++i) {
            int row = i * 32 + (t >> 3);
            int gchunk = (t & 7) ^ (row & 7);
            GLL16(Abase + (size_t)row * 512 + k0 + gchunk * 8, &As[buf][(i * 256 + t) * 8]);
        }
#pragma unroll
        for (int i = 0; i < 4; ++i) {
            int row = i * 32 + (t >> 3);
            int gchunk = (t & 7) ^ (row & 7);
            GLL16(Bbase + (size_t)row * 512 + k0 + gchunk * 8, &Bs[buf][(i * 256 + t) * 8]);
        }
    };
    STAGE(0, 0);
    STAGE(1, 64);
    for (int s = 0; s < 8; ++s) {
        if (s < 7) asm volatile("s_waitcnt vmcnt(6)" ::: "memory");
        else       asm volatile("s_waitcnt vmcnt(0)" ::: "memory");
        __builtin_amdgcn_s_barrier();
        const int cur = s & 1;
#pragma unroll
        for (int ks = 0; ks < 2; ++ks) {
            bf16x8 af[2], bfr[4];
            const int c8 = ks * 4 + quad;
#pragma unroll
            for (int mi = 0; mi < 2; ++mi) {
                int R = wr * 32 + mi * 16 + r15;
                af[mi] = *(const bf16x8*)(&As[cur][R * 64 + ((c8 ^ (R & 7)) * 8)]);
            }
#pragma unroll
            for (int j = 0; j < 4; ++j) {
                int R = wc * 64 + j * 16 + r15;
                bfr[j] = *(const bf16x8*)(&Bs[cur][R * 64 + ((c8 ^ (R & 7)) * 8)]);
            }
#pragma unroll
            for (int mi = 0; mi < 2; ++mi)
#pragma unroll
                for (int j = 0; j < 4; ++j)
                    acc[mi][j] = __builtin_amdgcn_mfma_f32_16x16x32_bf16(af[mi], bfr[j], acc[mi][j], 0, 0, 0);
        }
        __builtin_amdgcn_s_barrier();
        if (s + 2 < 8) STAGE(cur, (s + 2) * 64);
    }
    float lam = lamp[0];
#pragma unroll
    for (int mi = 0; mi < 2; ++mi) {
        size_t rowbase = (size_t)(b * 512 + ct * 64 + wr * 32 + mi * 16 + quad * 4);
#pragma unroll
        for (int j = 0; j < 4; ++j)
#pragma unroll
            for (int ii = 0; ii < 4; ++ii) {
                size_t idx = (rowbase + ii) * 1024 + pt * 128 + wc * 64 + j * 16 + r15;
                out[idx] = fq[idx] + lam * acc[mi][j][ii];
            }
    }
    float uv[2][4];
#pragma unroll
    for (int mi = 0; mi < 2; ++mi)
#pragma unroll
        for (int ii = 0; ii < 4; ++ii)
            uv[mi][ii] = u[ct * 64 + wr * 32 + mi * 16 + quad * 4 + ii];
#pragma unroll
    for (int j = 0; j < 4; ++j) {
        float pv = 0.f;
#pragma unroll
        for (int mi = 0; mi < 2; ++mi)
#pragma unroll
            for (int ii = 0; ii < 4; ++ii)
                pv += uv[mi][ii] * acc[mi][j][ii];
        pv += __shfl_xor(pv, 16, 64);
        pv += __shfl_xor(pv, 32, 64);
        if (lane < 16)
            atomicAdd(alog + (size_t)b * 1024 + pt * 128 + wc * 64 + j * 16 + r15, pv);
    }
    if (ct == 0) {
        __shared__ float coef[512];
        coef[t] = r[b * 512 + t] * wsq[t] * wsk[t] * (1.f / 256.f);
        coef[t + 256] = r[b * 512 + t + 256] * wsq[t + 256] * wsk[t + 256] * (1.f / 256.f);
        __syncthreads();
        int q = pt * 128 + (t & 127);
        int ch = t >> 7;
        const float* f = fsm32 + (size_t)(ch * 256) * 1024 + q;
        const float* cf = coef + ch * 256;
        float s0 = 0.f, s1 = 0.f, s2 = 0.f, s3 = 0.f;
#pragma unroll 4
        for (int ci = 0; ci < 256; ci += 4) {
            s0 += cf[ci] * f[(size_t)ci * 1024];
            s1 += cf[ci + 1] * f[(size_t)(ci + 1) * 1024];
            s2 += cf[ci + 2] * f[(size_t)(ci + 2) * 1024];
            s3 += cf[ci + 3] * f[(size_t)(ci + 3) * 1024];
        }
        atomicAdd(&blog[(size_t)b * 1024 + q], (s0 + s1) + (s2 + s3));
    }
}

// K7: z<16: alpha softmax -> out; z>=16: beta softmax -> atomic bmean;
// last-finishing beta block broadcasts bmean.
__global__ void k_softmax_rows(const float* __restrict__ alog, const float* __restrict__ blog,
                               float* __restrict__ alpha_out, float* __restrict__ bmean,
                               int* __restrict__ cnt, float* __restrict__ out_bmean) {
    int z = blockIdx.x;
    int t = threadIdx.x;
    int w = t >> 6, lane = t & 63;
    const float* src = (z < 16) ? (alog + (size_t)z * 1024) : (blog + (size_t)(z - 16) * 1024);
    float v[4];
    float mx = -3.4e38f;
#pragma unroll
    for (int j = 0; j < 4; ++j) {
        v[j] = src[t + 256 * j];
        mx = fmaxf(mx, v[j]);
    }
    __shared__ float red[4];
    float wm = wave_reduce_max(mx);
    if (lane == 0) red[w] = wm;
    __syncthreads();
    mx = fmaxf(fmaxf(red[0], red[1]), fmaxf(red[2], red[3]));
    float s = 0.f;
#pragma unroll
    for (int j = 0; j < 4; ++j) {
        v[j] = __expf(v[j] - mx);
        s += v[j];
    }
    __syncthreads();
    float ws_ = wave_reduce_sum(s);
    if (lane == 0) red[w] = ws_;
    __syncthreads();
    s = red[0] + red[1] + red[2] + red[3];
    float inv = 1.f / s;
    if (z < 16) {
#pragma unroll
        for (int j = 0; j < 4; ++j) alpha_out[(size_t)z * 1024 + t + 256 * j] = v[j] * inv;
    } else {
        float inv16 = inv * (1.f / 16.f);
#pragma unroll
        for (int j = 0; j < 4; ++j) atomicAdd(&bmean[t + 256 * j], v[j] * inv16);
        __threadfence();
        __syncthreads();
        __shared__ int lastflag;
        if (t == 0) lastflag = (atomicAdd(cnt, 1) == 15) ? 1 : 0;
        __syncthreads();
        if (lastflag) {
            __threadfence();
#pragma unroll
            for (int j = 0; j < 4; ++j) {
                int q = t + 256 * j;
                float val = __hip_atomic_load(&bmean[q], __ATOMIC_ACQUIRE, __HIP_MEMORY_SCOPE_AGENT);
#pragma unroll
                for (int si = 0; si < 16; ++si) out_bmean[(size_t)si * 1024 + q] = val;
            }
        }
    }
}

extern "C" void kernel_launch(void* const* d_in, const int* in_sizes, int n_in,
                              void* d_out, int out_size, void* d_ws, size_t ws_size,
                              hipStream_t stream) {
    const float* f_q = (const float*)d_in[0];
    const float* f_s = (const float*)d_in[1];
    const float* w_cca_q = (const float*)d_in[2];
    const float* w_cca_k = (const float*)d_in[3];
    const float* w_cca_v = (const float*)d_in[4];
    const float* w_sca_q = (const float*)d_in[5];
    const float* w_sca_k = (const float*)d_in[6];
    const float* lamp = (const float*)d_in[7];

    char* ws = (char*)d_ws;
    float* fsm32 = (float*)(ws + 0);             //  2 MB   [512,1024]
    bf16* fsm16 = (bf16*)(ws + 2097152);         //  1 MB
    bf16* fsmT = (bf16*)(ws + 3145728);          //  1 MB   [1024,512]
    bf16* Acw = (bf16*)(ws + 20971520);          //  8 MB   [16,512,512]
    bf16* fq16 = (bf16*)(ws + 29360128);         // 16.8 MB [16,512,1024]
    float* rmpartT = (float*)(ws + 46137344);    // 64 KB   [512,32]
    float* u = (float*)(ws + 46204928);          //  2 KB
    float* r = (float*)(ws + 46206976);          // 32 KB   [16,512]
    float* alog = (float*)(ws + 46239744);       // 64 KB  -- zbuf start (alog,blog,bmean,cnt)
    float* blog = (float*)(ws + 46305280);       // 64 KB
    float* bmean = (float*)(ws + 46370816);      //  4 KB
    int* cnt = (int*)(ws + 46374912);            //  1 KB

    float* out_fq = (float*)d_out;
    float* out_alpha = out_fq + 8388608;
    float* out_bmean = out_fq + 8404992;

    k_prep<<<dim3(32, 16), 256, 0, stream>>>(f_s, f_q, fsm32, fsm16, fsmT, fq16, rmpartT);
    k_fused1<<<dim3(16, 16), 512, 0, stream>>>(fq16, fsm16, w_cca_q, w_cca_k, w_cca_v,
                                               rmpartT, w_sca_q, w_sca_k, Acw, r, u, alog);
    k_gemm2<<<dim3(8, 8, 16), 256, 0, stream>>>(Acw, fsmT, f_q, lamp, u, r, w_sca_q, w_sca_k,
                                                fsm32, out_fq, alog, blog);
    k_softmax_rows<<<32, 256, 0, stream>>>(alog, blog, out_alpha, bmean, cnt, out_bmean);
}